// Round 2
// baseline (832.927 us; speedup 1.0000x reference)
//
#include <hip/hip_runtime.h>

#define BT 4096
#define H  2048
#define V  32000
#define BM 256
#define BN 256
#define BKB 128                   /* fp8 bytes per K-tile row */
#define KT (H / BKB)              /* 16 K-tiles */
#define NTILES (V / BN)           /* 125 */
#define MTILES (BT / BM)          /* 16 */
#define NWG (MTILES * NTILES)     /* 2000, % 8 == 0 -> bijective XCD swizzle */
#define IGNORE_INDEX (-100)

typedef int   v8i   __attribute__((ext_vector_type(8)));
typedef float f32x4 __attribute__((ext_vector_type(4)));

#define SCALE_ONE 0x7F7F7F7F        /* E8M0 127 = 2^0 in every byte */
#define UNSCALE   (1.0f / 65536.0f) /* inputs pre-scaled by 2^8 each */

#define BAR()   __builtin_amdgcn_s_barrier()
#define LGKM0() asm volatile("s_waitcnt lgkmcnt(0)" ::: "memory")
#define LGKM8() asm volatile("s_waitcnt lgkmcnt(8)" ::: "memory")
#define VMC(N)  asm volatile("s_waitcnt vmcnt(" #N ")" ::: "memory")

__device__ inline void load_lds16(const void* g, void* l) {
  __builtin_amdgcn_global_load_lds(
      (const __attribute__((address_space(1))) unsigned int*)g,
      (__attribute__((address_space(3))) unsigned int*)l,
      16, 0, 0);
}

// ---------------------------------------------------------- fp32 -> fp8 e4m3
__global__ __launch_bounds__(256)
void cvt_fp8_kernel(const float* __restrict__ in, unsigned int* __restrict__ out, long n8) {
  long i = (long)blockIdx.x * blockDim.x + threadIdx.x;
  long stride = (long)gridDim.x * blockDim.x;
  for (; i < n8; i += stride) {
    float4 x = ((const float4*)in)[2 * i];
    float4 y = ((const float4*)in)[2 * i + 1];
    int lo = 0, hi = 0;
    lo = __builtin_amdgcn_cvt_pk_fp8_f32(x.x * 256.f, x.y * 256.f, lo, false);
    lo = __builtin_amdgcn_cvt_pk_fp8_f32(x.z * 256.f, x.w * 256.f, lo, true);
    hi = __builtin_amdgcn_cvt_pk_fp8_f32(y.x * 256.f, y.y * 256.f, hi, false);
    hi = __builtin_amdgcn_cvt_pk_fp8_f32(y.z * 256.f, y.w * 256.f, hi, true);
    uint2 p; p.x = (unsigned)lo; p.y = (unsigned)hi;
    ((uint2*)out)[i] = p;
  }
}

// --------------------------------------------------------------------------
// 256x256-tile, 8-wave (2x4), 8-phase K-loop, MX-fp8 16x16x128 MFMA.
//
// LDS layout (fragment-contiguous): A tile = 16 frag-blocks (fb = row/16) of
// 2 KB. Within a frag-block: plane c (0/1) of 1 KB, slot lane*16 holds
// (row = fb*16 + (lane&15), kbytes = 32*(lane>>4) + 16*c .. +16).
// => MFMA fragment read for lane = {base + fb*2048 + lane*16,  +1024} —
// perfectly linear 16B/lane, bank-conflict-free by construction, one address
// VGPR + immediate offsets. The permutation is applied on the per-lane
// GLOBAL source address of global_load_lds (LDS dest stays linear).
//
// Stage slots (race-free ledger, 1 half-tile = 2 gload_lds per phase):
//   ph0: buf1.A0 <- t1   ph1: buf1.A1 <- t1
//   ph2: buf0.B0 <- t0+2 ph3: buf0.B1 <- t0+2 ; vmcnt(4)
//   ph4: buf0.A0 <- t0+2 ph5: buf0.A1 <- t0+2
//   ph6: buf1.B0 <- t1+2 ph7: buf1.B1 <- t1+2 ; vmcnt(4)
// Reads: ph0: fa0-3,fb0-1(buf0) ph1: fb2-3 ph2: fa4-7 ph3: none (buf1 ditto
// at ph4-7). Every overwrite lands >=1 phase after the last completed read;
// every read is covered by the preceding counted vmcnt.
// --------------------------------------------------------------------------
union frag_u { v8i v; int4 h[2]; };

#define MF(C, A, B)                                                         \
  (C) = __builtin_amdgcn_mfma_scale_f32_16x16x128_f8f6f4(                   \
      (A).v, (B).v, (C), 0, 0, 0, SCALE_ONE, 0, SCALE_ONE)

__global__ __launch_bounds__(512, 2)
void gemm_lse_kernel(const unsigned char* __restrict__ Af8,
                     const unsigned char* __restrict__ Bf8,
                     const int* __restrict__ tgt,
                     float* __restrict__ pm, float* __restrict__ pl,
                     float* __restrict__ tl) {
  __shared__ __align__(16) unsigned char As[2 * 32768];  // 64 KB
  __shared__ __align__(16) unsigned char Bs[2 * 32768];  // 64 KB
  __shared__ float red_m[4][BM];
  __shared__ float red_l[4][BM];
  __shared__ int   stgt[BM];

  // T1: bijective XCD swizzle (2000 % 8 == 0), mt fastest within an XCD:
  // 16 consecutive blocks share one B-panel (L2), A is L3-resident.
  const int wgid = ((int)blockIdx.x & 7) * (NWG / 8) + ((int)blockIdx.x >> 3);
  const int mt = wgid & (MTILES - 1);
  const int nt = wgid / MTILES;
  const int m0 = mt * BM;
  const int n0 = nt * BN;

  const int tid  = threadIdx.x;
  const int lane = tid & 63;
  const int w    = tid >> 6;   // wave 0..7
  const int wr   = w >> 2;     // 0..1 : rows [wr*128, +128)
  const int wc   = w & 3;      // 0..3 : cols [wc*64, +64)
  const int lm   = lane & 15;
  const int q    = lane >> 4;  // k-chunk selector

  if (tid < BM) stgt[tid] = tgt[m0 + tid];
  __syncthreads();  // drains stgt's vmcnt before counted staging begins

  // staging source (per-lane permuted): lane l of wave w fetches, for
  // window c: row m0 + hf*128 + w*16 + (l&15), kbytes (l>>4)*32 + c*16.
  const unsigned char* aSrc = Af8 + (size_t)(m0 + w * 16 + lm) * H + q * 32;
  const unsigned char* bSrc = Bf8 + (size_t)(n0 + w * 16 + lm) * H + q * 32;

  auto stageA = [&](int buf, int hf, int kt) {
    const unsigned char* s = aSrc + (size_t)hf * 128 * H + (size_t)kt * BKB;
    unsigned char* d = As + buf * 32768 + (hf * 8 + w) * 2048;
    load_lds16(s, d);             // plane c=0
    load_lds16(s + 16, d + 1024); // plane c=1
  };
  auto stageB = [&](int buf, int hf, int kt) {
    const unsigned char* s = bSrc + (size_t)hf * 128 * H + (size_t)kt * BKB;
    unsigned char* d = Bs + buf * 32768 + (hf * 8 + w) * 2048;
    load_lds16(s, d);
    load_lds16(s + 16, d + 1024);
  };

  // fragment reads: one per-lane address, immediate offsets only.
  const unsigned char* aRd = As + lane * 16;
  const unsigned char* bRd = Bs + lane * 16;

  auto ldA = [&](frag_u& f, int buf, int i) {
    const unsigned char* p = aRd + buf * 32768 + (wr * 8 + i) * 2048;
    f.h[0] = *(const int4*)(p);
    f.h[1] = *(const int4*)(p + 1024);
  };
  auto ldB = [&](frag_u& f, int buf, int j) {
    const unsigned char* p = bRd + buf * 32768 + (wc * 4 + j) * 2048;
    f.h[0] = *(const int4*)(p);
    f.h[1] = *(const int4*)(p + 1024);
  };

  f32x4 acc[8][4];
#pragma unroll
  for (int a = 0; a < 8; ++a)
#pragma unroll
    for (int b = 0; b < 4; ++b) acc[a][b] = (f32x4){0.f, 0.f, 0.f, 0.f};

  frag_u fa0, fa1, fa2, fa3, fb0, fb1, fb2, fb3;

  // ---- prologue: tile0 (buf0) fully + tile1 B -> buf1; buf0 guaranteed.
  stageA(0, 0, 0); stageA(0, 1, 0); stageB(0, 0, 0); stageB(0, 1, 0);
  stageB(1, 0, 1); stageB(1, 1, 1);
  VMC(4);
  BAR();

  for (int i = 0; i < 8; ++i) {
    const int t0 = 2 * i, t1 = 2 * i + 1;
    const bool pre = (i < 7);

    // ---- phase 0: buf0, a0-3 x b0-1
    ldA(fa0, 0, 0); ldA(fa1, 0, 1); ldA(fa2, 0, 2); ldA(fa3, 0, 3);
    ldB(fb0, 0, 0); ldB(fb1, 0, 1);
    stageA(1, 0, t1);
    LGKM8();
    BAR(); LGKM0();
    __builtin_amdgcn_s_setprio(1);
    MF(acc[0][0], fa0, fb0); MF(acc[1][0], fa1, fb0);
    MF(acc[2][0], fa2, fb0); MF(acc[3][0], fa3, fb0);
    MF(acc[0][1], fa0, fb1); MF(acc[1][1], fa1, fb1);
    MF(acc[2][1], fa2, fb1); MF(acc[3][1], fa3, fb1);
    __builtin_amdgcn_s_setprio(0);
    BAR();

    // ---- phase 1: a0-3 x b2-3
    ldB(fb2, 0, 2); ldB(fb3, 0, 3);
    stageA(1, 1, t1);
    BAR(); LGKM0();
    __builtin_amdgcn_s_setprio(1);
    MF(acc[0][2], fa0, fb2); MF(acc[1][2], fa1, fb2);
    MF(acc[2][2], fa2, fb2); MF(acc[3][2], fa3, fb2);
    MF(acc[0][3], fa0, fb3); MF(acc[1][3], fa1, fb3);
    MF(acc[2][3], fa2, fb3); MF(acc[3][3], fa3, fb3);
    __builtin_amdgcn_s_setprio(0);
    BAR();

    // ---- phase 2: a4-7 x b0-1
    ldA(fa0, 0, 4); ldA(fa1, 0, 5); ldA(fa2, 0, 6); ldA(fa3, 0, 7);
    if (pre) stageB(0, 0, t0 + 2);
    BAR(); LGKM0();
    __builtin_amdgcn_s_setprio(1);
    MF(acc[4][0], fa0, fb0); MF(acc[5][0], fa1, fb0);
    MF(acc[6][0], fa2, fb0); MF(acc[7][0], fa3, fb0);
    MF(acc[4][1], fa0, fb1); MF(acc[5][1], fa1, fb1);
    MF(acc[6][1], fa2, fb1); MF(acc[7][1], fa3, fb1);
    __builtin_amdgcn_s_setprio(0);
    BAR();

    // ---- phase 3: a4-7 x b2-3
    if (pre) stageB(0, 1, t0 + 2);
    BAR(); LGKM0();
    __builtin_amdgcn_s_setprio(1);
    MF(acc[4][2], fa0, fb2); MF(acc[5][2], fa1, fb2);
    MF(acc[6][2], fa2, fb2); MF(acc[7][2], fa3, fb2);
    MF(acc[4][3], fa0, fb3); MF(acc[5][3], fa1, fb3);
    MF(acc[6][3], fa2, fb3); MF(acc[7][3], fa3, fb3);
    __builtin_amdgcn_s_setprio(0);
    if (pre) { VMC(4); } else { VMC(0); }   // buf1 (tile t1) fully landed
    BAR();

    // ---- phase 4: buf1, a0-3 x b0-1
    ldA(fa0, 1, 0); ldA(fa1, 1, 1); ldA(fa2, 1, 2); ldA(fa3, 1, 3);
    ldB(fb0, 1, 0); ldB(fb1, 1, 1);
    if (pre) stageA(0, 0, t0 + 2);
    LGKM8();
    BAR(); LGKM0();
    __builtin_amdgcn_s_setprio(1);
    MF(acc[0][0], fa0, fb0); MF(acc[1][0], fa1, fb0);
    MF(acc[2][0], fa2, fb0); MF(acc[3][0], fa3, fb0);
    MF(acc[0][1], fa0, fb1); MF(acc[1][1], fa1, fb1);
    MF(acc[2][1], fa2, fb1); MF(acc[3][1], fa3, fb1);
    __builtin_amdgcn_s_setprio(0);
    BAR();

    // ---- phase 5: a0-3 x b2-3
    ldB(fb2, 1, 2); ldB(fb3, 1, 3);
    if (pre) stageA(0, 1, t0 + 2);
    BAR(); LGKM0();
    __builtin_amdgcn_s_setprio(1);
    MF(acc[0][2], fa0, fb2); MF(acc[1][2], fa1, fb2);
    MF(acc[2][2], fa2, fb2); MF(acc[3][2], fa3, fb2);
    MF(acc[0][3], fa0, fb3); MF(acc[1][3], fa1, fb3);
    MF(acc[2][3], fa2, fb3); MF(acc[3][3], fa3, fb3);
    __builtin_amdgcn_s_setprio(0);
    BAR();

    // ---- phase 6: a4-7 x b0-1
    ldA(fa0, 1, 4); ldA(fa1, 1, 5); ldA(fa2, 1, 6); ldA(fa3, 1, 7);
    if (pre) stageB(1, 0, t1 + 2);
    BAR(); LGKM0();
    __builtin_amdgcn_s_setprio(1);
    MF(acc[4][0], fa0, fb0); MF(acc[5][0], fa1, fb0);
    MF(acc[6][0], fa2, fb0); MF(acc[7][0], fa3, fb0);
    MF(acc[4][1], fa0, fb1); MF(acc[5][1], fa1, fb1);
    MF(acc[6][1], fa2, fb1); MF(acc[7][1], fa3, fb1);
    __builtin_amdgcn_s_setprio(0);
    BAR();

    // ---- phase 7: a4-7 x b2-3
    if (pre) stageB(1, 1, t1 + 2);
    BAR(); LGKM0();
    __builtin_amdgcn_s_setprio(1);
    MF(acc[4][2], fa0, fb2); MF(acc[5][2], fa1, fb2);
    MF(acc[6][2], fa2, fb2); MF(acc[7][2], fa3, fb2);
    MF(acc[4][3], fa0, fb3); MF(acc[5][3], fa1, fb3);
    MF(acc[6][3], fa2, fb3); MF(acc[7][3], fa3, fb3);
    __builtin_amdgcn_s_setprio(0);
    if (pre) { VMC(4); } else { VMC(0); }   // buf0 (tile t0+2) fully landed
    BAR();
  }

  __syncthreads();

  // ---- target-logit extraction (C layout: col=lane&15, row=q*4+reg)
#pragma unroll
  for (int ai = 0; ai < 8; ++ai) {
#pragma unroll
    for (int r = 0; r < 4; ++r) {
      int row_local = wr * 128 + ai * 16 + q * 4 + r;
      int c = stgt[row_local] - n0 - wc * 64;
      if ((unsigned)c < 64u && (c & 15) == lm) {
        int bj = c >> 4;
        float v = bj == 0 ? acc[ai][0][r]
                : bj == 1 ? acc[ai][1][r]
                : bj == 2 ? acc[ai][2][r]
                :           acc[ai][3][r];
        tl[m0 + row_local] = v * UNSCALE;
      }
    }
  }

  // ---- per-row (max, sumexp) over this wave's 64 columns
#pragma unroll
  for (int ai = 0; ai < 8; ++ai) {
#pragma unroll
    for (int r = 0; r < 4; ++r) {
      float v0 = acc[ai][0][r] * UNSCALE;
      float v1 = acc[ai][1][r] * UNSCALE;
      float v2 = acc[ai][2][r] * UNSCALE;
      float v3 = acc[ai][3][r] * UNSCALE;
      float mx = fmaxf(fmaxf(v0, v1), fmaxf(v2, v3));
#pragma unroll
      for (int off = 1; off < 16; off <<= 1) mx = fmaxf(mx, __shfl_xor(mx, off));
      float s = __expf(v0 - mx) + __expf(v1 - mx) + __expf(v2 - mx) + __expf(v3 - mx);
#pragma unroll
      for (int off = 1; off < 16; off <<= 1) s += __shfl_xor(s, off);
      if (lm == 0) {
        int row_local = wr * 128 + ai * 16 + q * 4 + r;
        red_m[wc][row_local] = mx;
        red_l[wc][row_local] = s;
      }
    }
  }
  __syncthreads();
  if (tid < BM) {
    float M = fmaxf(fmaxf(red_m[0][tid], red_m[1][tid]),
                    fmaxf(red_m[2][tid], red_m[3][tid]));
    float L = red_l[0][tid] * __expf(red_m[0][tid] - M)
            + red_l[1][tid] * __expf(red_m[1][tid] - M)
            + red_l[2][tid] * __expf(red_m[2][tid] - M)
            + red_l[3][tid] * __expf(red_m[3][tid] - M);
    long idx = (long)nt * BT + (m0 + tid);
    pm[idx] = M;
    pl[idx] = L;
  }
}

// -------------------------------------------- combine partials, wave per row
__global__ __launch_bounds__(256)
void row_lse_kernel(const float* __restrict__ pm, const float* __restrict__ pl,
                    const float* __restrict__ tl, const int* __restrict__ tgt,
                    float* __restrict__ rl) {
  int row  = blockIdx.x * 4 + (threadIdx.x >> 6);
  int lane = threadIdx.x & 63;
  float M = -__builtin_inff();
  float L = 0.f;
  for (int t = lane; t < NTILES; t += 64) {
    float m2 = pm[(long)t * BT + row];
    float l2 = pl[(long)t * BT + row];
    float Mn = fmaxf(M, m2);
    L = L * __expf(M - Mn) + l2 * __expf(m2 - Mn);
    M = Mn;
  }
#pragma unroll
  for (int off = 1; off < 64; off <<= 1) {
    float m2 = __shfl_xor(M, off);
    float l2 = __shfl_xor(L, off);
    float Mn = fmaxf(M, m2);
    L = L * __expf(M - Mn) + l2 * __expf(m2 - Mn);
    M = Mn;
  }
  if (lane == 0) {
    float lse = M + logf(L);
    int t = tgt[row];
    rl[row] = (t != IGNORE_INDEX) ? (lse - tl[row]) : 0.f;
  }
}

// ------------------------------------------------------------- final reduce
__global__ __launch_bounds__(256)
void final_kernel(const float* __restrict__ rl, const int* __restrict__ tgt,
                  float* __restrict__ out) {
  __shared__ float ss[4];
  __shared__ float sc[4];
  float s = 0.f, c = 0.f;
  for (int r = threadIdx.x; r < BT; r += 256) {
    s += rl[r];
    c += (tgt[r] != IGNORE_INDEX) ? 1.f : 0.f;
  }
#pragma unroll
  for (int off = 32; off > 0; off >>= 1) {
    s += __shfl_xor(s, off);
    c += __shfl_xor(c, off);
  }
  int w = threadIdx.x >> 6;
  if ((threadIdx.x & 63) == 0) { ss[w] = s; sc[w] = c; }
  __syncthreads();
  if (threadIdx.x == 0) {
    float S = ss[0] + ss[1] + ss[2] + ss[3];
    float C = sc[0] + sc[1] + sc[2] + sc[3];
    out[0] = S / fmaxf(C, 1.f);
  }
}

extern "C" void kernel_launch(void* const* d_in, const int* in_sizes, int n_in,
                              void* d_out, int out_size, void* d_ws, size_t ws_size,
                              hipStream_t stream) {
  const float* hs  = (const float*)d_in[0];   // hidden_states [BT][H] fp32
  const float* wt  = (const float*)d_in[1];   // weight [V][H] fp32
  const int*   tgt = (const int*)d_in[2];     // targets [BT]
  float*       out = (float*)d_out;

  char* ws = (char*)d_ws;
  size_t off = 0;
  auto alloc = [&](size_t bytes) -> void* {
    void* p = ws + off;
    off += (bytes + 255) & ~(size_t)255;
    return p;
  };
  unsigned char* wf8 = (unsigned char*)alloc((size_t)V * H);        // 65.5 MB
  unsigned char* hf8 = (unsigned char*)alloc((size_t)BT * H);       // 8.4 MB
  float* pm = (float*)alloc((size_t)NTILES * BT * 4);               // 2.0 MB
  float* pl = (float*)alloc((size_t)NTILES * BT * 4);               // 2.0 MB
  float* tl = (float*)alloc((size_t)BT * 4);
  float* rl = (float*)alloc((size_t)BT * 4);
  (void)ws_size; (void)in_sizes; (void)n_in; (void)out_size;

  cvt_fp8_kernel<<<8192, 256, 0, stream>>>(wt, (unsigned int*)wf8, (long)V * H / 8);
  cvt_fp8_kernel<<<1024, 256, 0, stream>>>(hs, (unsigned int*)hf8, (long)BT * H / 8);

  gemm_lse_kernel<<<NWG, 512, 0, stream>>>(hf8, wf8, tgt, pm, pl, tl);

  row_lse_kernel<<<BT / 4, 256, 0, stream>>>(pm, pl, tl, tgt, rl);
  final_kernel<<<1, 256, 0, stream>>>(rl, tgt, out);
}

// Round 3
// 709.464 us; speedup vs baseline: 1.1740x; 1.1740x over previous
//
#include <hip/hip_runtime.h>

#define BT 4096
#define H  2048
#define V  32000
#define BM 256
#define BN 256
#define BKB 128                   /* fp8 bytes per K-tile row */
#define KT (H / BKB)              /* 16 K-tiles */
#define NTILES (V / BN)           /* 125 */
#define MTILES (BT / BM)          /* 16 */
#define NWG (MTILES * NTILES)     /* 2000, % 8 == 0 -> bijective XCD swizzle */
#define IGNORE_INDEX (-100)

typedef int   v8i   __attribute__((ext_vector_type(8)));
typedef float f32x4 __attribute__((ext_vector_type(4)));

#define SCALE_ONE 0x7F7F7F7F        /* E8M0 127 = 2^0 in every byte */
#define UNSCALE   (1.0f / 65536.0f) /* inputs pre-scaled by 2^8 each */

#define BAR()   __builtin_amdgcn_s_barrier()
#define LGKM0() asm volatile("s_waitcnt lgkmcnt(0)" ::: "memory")
#define LGKM8() asm volatile("s_waitcnt lgkmcnt(8)" ::: "memory")
#define VMC(N)  asm volatile("s_waitcnt vmcnt(" #N ")" ::: "memory")

__device__ inline void load_lds16(const void* g, void* l) {
  __builtin_amdgcn_global_load_lds(
      (const __attribute__((address_space(1))) unsigned int*)g,
      (__attribute__((address_space(3))) unsigned int*)l,
      16, 0, 0);
}

// ------------------------------------------- fp32 -> fp8 e4m3, FRAG-PACKED
// One wave per (row-group g, K-tile kt). Output 2KB block layout:
//   byte [c*1024 + lane*16 + b] = fp8( in[g*16 + (lane&15)]
//                                       [kt*128 + (lane>>4)*32 + c*16 + b] )
// This is exactly the MFMA fragment order, so GEMM staging becomes a pure
// contiguous 1KB copy per global_load_lds (minimal memory transactions),
// LDS stays linear, fragment ds_reads stay linear (0 bank conflicts).
__global__ __launch_bounds__(256)
void cvt_pack_kernel(const float* __restrict__ in, unsigned char* __restrict__ out,
                     int tasks) {
  int task = blockIdx.x * 4 + (threadIdx.x >> 6);
  if (task >= tasks) return;
  const int g    = task >> 4;          // KT = 16
  const int kt   = task & 15;
  const int lane = threadIdx.x & 63;
  const float* src = in + (size_t)(g * 16 + (lane & 15)) * H
                        + kt * 128 + (lane >> 4) * 32;
  int p[8];
#pragma unroll
  for (int u = 0; u < 8; ++u) {        // floats 4u..4u+3 -> bytes 4u..4u+3
    float4 x = ((const float4*)src)[u];
    int v = 0;
    v = __builtin_amdgcn_cvt_pk_fp8_f32(x.x * 256.f, x.y * 256.f, v, false);
    v = __builtin_amdgcn_cvt_pk_fp8_f32(x.z * 256.f, x.w * 256.f, v, true);
    p[u] = v;
  }
  unsigned char* dst = out + ((size_t)g * KT + kt) * 2048 + lane * 16;
  int4 lo; lo.x = p[0]; lo.y = p[1]; lo.z = p[2]; lo.w = p[3];
  int4 hi; hi.x = p[4]; hi.y = p[5]; hi.z = p[6]; hi.w = p[7];
  *(int4*)dst          = lo;           // plane c=0 (k-bytes +0..15)
  *(int4*)(dst + 1024) = hi;           // plane c=1 (k-bytes +16..31)
}

// --------------------------------------------------------------------------
// 256x256-tile, 8-wave (2x4), 8-phase K-loop, MX-fp8 16x16x128 MFMA.
// Operands are pre-packed in fragment order (see cvt_pack_kernel), so:
//   staging   = contiguous 1KB global_load_lds (8x128B tx each)
//   LDS       = linear frag-blocks of 2KB (plane0 | plane1)
//   frag read = base + lane*16 (+1024), conflict-free by construction
// Stage slots (race-free ledger, verified R2, unchanged):
//   ph0: buf1.A0 <- t1   ph1: buf1.A1 <- t1
//   ph2: buf0.B0 <- t0+2 ph3: buf0.B1 <- t0+2 ; vmcnt(4)
//   ph4: buf0.A0 <- t0+2 ph5: buf0.A1 <- t0+2
//   ph6: buf1.B0 <- t1+2 ph7: buf1.B1 <- t1+2 ; vmcnt(4)
// --------------------------------------------------------------------------
union frag_u { v8i v; int4 h[2]; };

#define MF(C, A, B)                                                         \
  (C) = __builtin_amdgcn_mfma_scale_f32_16x16x128_f8f6f4(                   \
      (A).v, (B).v, (C), 0, 0, 0, SCALE_ONE, 0, SCALE_ONE)

__global__ __launch_bounds__(512, 2)
void gemm_lse_kernel(const unsigned char* __restrict__ Af8,
                     const unsigned char* __restrict__ Bf8,
                     const int* __restrict__ tgt,
                     float* __restrict__ pm, float* __restrict__ pl,
                     float* __restrict__ tl) {
  __shared__ __align__(16) unsigned char As[2 * 32768];  // 64 KB
  __shared__ __align__(16) unsigned char Bs[2 * 32768];  // 64 KB
  __shared__ float red_m[4][BM];
  __shared__ float red_l[4][BM];
  __shared__ int   stgt[BM];

  // T1: bijective XCD swizzle (2000 % 8 == 0), mt fastest within an XCD:
  // 16 consecutive blocks share one 512KB B-panel (L2), A is L3-resident.
  const int wgid = ((int)blockIdx.x & 7) * (NWG / 8) + ((int)blockIdx.x >> 3);
  const int mt = wgid & (MTILES - 1);
  const int nt = wgid / MTILES;
  const int m0 = mt * BM;
  const int n0 = nt * BN;

  const int tid  = threadIdx.x;
  const int lane = tid & 63;
  const int w    = tid >> 6;   // wave 0..7
  const int wr   = w >> 2;     // 0..1 : rows [wr*128, +128)
  const int wc   = w & 3;      // 0..3 : cols [wc*64, +64)
  const int lm   = lane & 15;
  const int q    = lane >> 4;

  if (tid < BM) stgt[tid] = tgt[m0 + tid];
  __syncthreads();  // drains stgt's vmcnt before counted staging begins

  // packed source: row-group (m0/16 + hf*8 + w), K-tile kt, 2KB contiguous.
  const unsigned char* aSrc = Af8 + (size_t)(m0 / 16) * KT * 2048;
  const unsigned char* bSrc = Bf8 + (size_t)(n0 / 16) * KT * 2048;

  auto stageA = [&](int buf, int hf, int kt) {
    const unsigned char* s = aSrc + ((size_t)(hf * 8 + w) * KT + kt) * 2048;
    unsigned char* d = As + buf * 32768 + (hf * 8 + w) * 2048;
    load_lds16(s, d);              // plane 0 (contiguous 1KB)
    load_lds16(s + 1024, d + 1024);// plane 1 (contiguous 1KB)
  };
  auto stageB = [&](int buf, int hf, int kt) {
    const unsigned char* s = bSrc + ((size_t)(hf * 8 + w) * KT + kt) * 2048;
    unsigned char* d = Bs + buf * 32768 + (hf * 8 + w) * 2048;
    load_lds16(s, d);
    load_lds16(s + 1024, d + 1024);
  };

  // fragment reads: one per-lane address, immediate offsets only.
  const unsigned char* aRd = As + lane * 16;
  const unsigned char* bRd = Bs + lane * 16;

  auto ldA = [&](frag_u& f, int buf, int i) {
    const unsigned char* p = aRd + buf * 32768 + (wr * 8 + i) * 2048;
    f.h[0] = *(const int4*)(p);
    f.h[1] = *(const int4*)(p + 1024);
  };
  auto ldB = [&](frag_u& f, int buf, int j) {
    const unsigned char* p = bRd + buf * 32768 + (wc * 4 + j) * 2048;
    f.h[0] = *(const int4*)(p);
    f.h[1] = *(const int4*)(p + 1024);
  };

  f32x4 acc[8][4];
#pragma unroll
  for (int a = 0; a < 8; ++a)
#pragma unroll
    for (int b = 0; b < 4; ++b) acc[a][b] = (f32x4){0.f, 0.f, 0.f, 0.f};

  frag_u fa0, fa1, fa2, fa3, fb0, fb1, fb2, fb3;

  // ---- prologue: tile0 (buf0) fully + tile1 B -> buf1; buf0 guaranteed.
  stageA(0, 0, 0); stageA(0, 1, 0); stageB(0, 0, 0); stageB(0, 1, 0);
  stageB(1, 0, 1); stageB(1, 1, 1);
  VMC(4);
  BAR();

  for (int i = 0; i < 8; ++i) {
    const int t0 = 2 * i, t1 = 2 * i + 1;
    const bool pre = (i < 7);

    // ---- phase 0: buf0, a0-3 x b0-1
    ldA(fa0, 0, 0); ldA(fa1, 0, 1); ldA(fa2, 0, 2); ldA(fa3, 0, 3);
    ldB(fb0, 0, 0); ldB(fb1, 0, 1);
    stageA(1, 0, t1);
    LGKM8();
    BAR(); LGKM0();
    __builtin_amdgcn_s_setprio(1);
    MF(acc[0][0], fa0, fb0); MF(acc[1][0], fa1, fb0);
    MF(acc[2][0], fa2, fb0); MF(acc[3][0], fa3, fb0);
    MF(acc[0][1], fa0, fb1); MF(acc[1][1], fa1, fb1);
    MF(acc[2][1], fa2, fb1); MF(acc[3][1], fa3, fb1);
    __builtin_amdgcn_s_setprio(0);
    BAR();

    // ---- phase 1: a0-3 x b2-3
    ldB(fb2, 0, 2); ldB(fb3, 0, 3);
    stageA(1, 1, t1);
    BAR(); LGKM0();
    __builtin_amdgcn_s_setprio(1);
    MF(acc[0][2], fa0, fb2); MF(acc[1][2], fa1, fb2);
    MF(acc[2][2], fa2, fb2); MF(acc[3][2], fa3, fb2);
    MF(acc[0][3], fa0, fb3); MF(acc[1][3], fa1, fb3);
    MF(acc[2][3], fa2, fb3); MF(acc[3][3], fa3, fb3);
    __builtin_amdgcn_s_setprio(0);
    BAR();

    // ---- phase 2: a4-7 x b0-1
    ldA(fa0, 0, 4); ldA(fa1, 0, 5); ldA(fa2, 0, 6); ldA(fa3, 0, 7);
    if (pre) stageB(0, 0, t0 + 2);
    BAR(); LGKM0();
    __builtin_amdgcn_s_setprio(1);
    MF(acc[4][0], fa0, fb0); MF(acc[5][0], fa1, fb0);
    MF(acc[6][0], fa2, fb0); MF(acc[7][0], fa3, fb0);
    MF(acc[4][1], fa0, fb1); MF(acc[5][1], fa1, fb1);
    MF(acc[6][1], fa2, fb1); MF(acc[7][1], fa3, fb1);
    __builtin_amdgcn_s_setprio(0);
    BAR();

    // ---- phase 3: a4-7 x b2-3
    if (pre) stageB(0, 1, t0 + 2);
    BAR(); LGKM0();
    __builtin_amdgcn_s_setprio(1);
    MF(acc[4][2], fa0, fb2); MF(acc[5][2], fa1, fb2);
    MF(acc[6][2], fa2, fb2); MF(acc[7][2], fa3, fb2);
    MF(acc[4][3], fa0, fb3); MF(acc[5][3], fa1, fb3);
    MF(acc[6][3], fa2, fb3); MF(acc[7][3], fa3, fb3);
    __builtin_amdgcn_s_setprio(0);
    if (pre) { VMC(4); } else { VMC(0); }   // buf1 (tile t1) fully landed
    BAR();

    // ---- phase 4: buf1, a0-3 x b0-1
    ldA(fa0, 1, 0); ldA(fa1, 1, 1); ldA(fa2, 1, 2); ldA(fa3, 1, 3);
    ldB(fb0, 1, 0); ldB(fb1, 1, 1);
    if (pre) stageA(0, 0, t0 + 2);
    LGKM8();
    BAR(); LGKM0();
    __builtin_amdgcn_s_setprio(1);
    MF(acc[0][0], fa0, fb0); MF(acc[1][0], fa1, fb0);
    MF(acc[2][0], fa2, fb0); MF(acc[3][0], fa3, fb0);
    MF(acc[0][1], fa0, fb1); MF(acc[1][1], fa1, fb1);
    MF(acc[2][1], fa2, fb1); MF(acc[3][1], fa3, fb1);
    __builtin_amdgcn_s_setprio(0);
    BAR();

    // ---- phase 5: a0-3 x b2-3
    ldB(fb2, 1, 2); ldB(fb3, 1, 3);
    if (pre) stageA(0, 1, t0 + 2);
    BAR(); LGKM0();
    __builtin_amdgcn_s_setprio(1);
    MF(acc[0][2], fa0, fb2); MF(acc[1][2], fa1, fb2);
    MF(acc[2][2], fa2, fb2); MF(acc[3][2], fa3, fb2);
    MF(acc[0][3], fa0, fb3); MF(acc[1][3], fa1, fb3);
    MF(acc[2][3], fa2, fb3); MF(acc[3][3], fa3, fb3);
    __builtin_amdgcn_s_setprio(0);
    BAR();

    // ---- phase 6: a4-7 x b0-1
    ldA(fa0, 1, 4); ldA(fa1, 1, 5); ldA(fa2, 1, 6); ldA(fa3, 1, 7);
    if (pre) stageB(1, 0, t1 + 2);
    BAR(); LGKM0();
    __builtin_amdgcn_s_setprio(1);
    MF(acc[4][0], fa0, fb0); MF(acc[5][0], fa1, fb0);
    MF(acc[6][0], fa2, fb0); MF(acc[7][0], fa3, fb0);
    MF(acc[4][1], fa0, fb1); MF(acc[5][1], fa1, fb1);
    MF(acc[6][1], fa2, fb1); MF(acc[7][1], fa3, fb1);
    __builtin_amdgcn_s_setprio(0);
    BAR();

    // ---- phase 7: a4-7 x b2-3
    if (pre) stageB(1, 1, t1 + 2);
    BAR(); LGKM0();
    __builtin_amdgcn_s_setprio(1);
    MF(acc[4][2], fa0, fb2); MF(acc[5][2], fa1, fb2);
    MF(acc[6][2], fa2, fb2); MF(acc[7][2], fa3, fb2);
    MF(acc[4][3], fa0, fb3); MF(acc[5][3], fa1, fb3);
    MF(acc[6][3], fa2, fb3); MF(acc[7][3], fa3, fb3);
    __builtin_amdgcn_s_setprio(0);
    if (pre) { VMC(4); } else { VMC(0); }   // buf0 (tile t0+2) fully landed
    BAR();
  }

  __syncthreads();

  // ---- target-logit extraction (C layout: col=lane&15, row=q*4+reg)
#pragma unroll
  for (int ai = 0; ai < 8; ++ai) {
#pragma unroll
    for (int r = 0; r < 4; ++r) {
      int row_local = wr * 128 + ai * 16 + q * 4 + r;
      int c = stgt[row_local] - n0 - wc * 64;
      if ((unsigned)c < 64u && (c & 15) == lm) {
        int bj = c >> 4;
        float v = bj == 0 ? acc[ai][0][r]
                : bj == 1 ? acc[ai][1][r]
                : bj == 2 ? acc[ai][2][r]
                :           acc[ai][3][r];
        tl[m0 + row_local] = v * UNSCALE;
      }
    }
  }

  // ---- per-row (max, sumexp) over this wave's 64 columns
#pragma unroll
  for (int ai = 0; ai < 8; ++ai) {
#pragma unroll
    for (int r = 0; r < 4; ++r) {
      float v0 = acc[ai][0][r] * UNSCALE;
      float v1 = acc[ai][1][r] * UNSCALE;
      float v2 = acc[ai][2][r] * UNSCALE;
      float v3 = acc[ai][3][r] * UNSCALE;
      float mx = fmaxf(fmaxf(v0, v1), fmaxf(v2, v3));
#pragma unroll
      for (int off = 1; off < 16; off <<= 1) mx = fmaxf(mx, __shfl_xor(mx, off));
      float s = __expf(v0 - mx) + __expf(v1 - mx) + __expf(v2 - mx) + __expf(v3 - mx);
#pragma unroll
      for (int off = 1; off < 16; off <<= 1) s += __shfl_xor(s, off);
      if (lm == 0) {
        int row_local = wr * 128 + ai * 16 + q * 4 + r;
        red_m[wc][row_local] = mx;
        red_l[wc][row_local] = s;
      }
    }
  }
  __syncthreads();
  if (tid < BM) {
    float M = fmaxf(fmaxf(red_m[0][tid], red_m[1][tid]),
                    fmaxf(red_m[2][tid], red_m[3][tid]));
    float L = red_l[0][tid] * __expf(red_m[0][tid] - M)
            + red_l[1][tid] * __expf(red_m[1][tid] - M)
            + red_l[2][tid] * __expf(red_m[2][tid] - M)
            + red_l[3][tid] * __expf(red_m[3][tid] - M);
    long idx = (long)nt * BT + (m0 + tid);
    pm[idx] = M;
    pl[idx] = L;
  }
}

// -------------------------------------------- combine partials, wave per row
__global__ __launch_bounds__(256)
void row_lse_kernel(const float* __restrict__ pm, const float* __restrict__ pl,
                    const float* __restrict__ tl, const int* __restrict__ tgt,
                    float* __restrict__ rl) {
  int row  = blockIdx.x * 4 + (threadIdx.x >> 6);
  int lane = threadIdx.x & 63;
  float M = -__builtin_inff();
  float L = 0.f;
  for (int t = lane; t < NTILES; t += 64) {
    float m2 = pm[(long)t * BT + row];
    float l2 = pl[(long)t * BT + row];
    float Mn = fmaxf(M, m2);
    L = L * __expf(M - Mn) + l2 * __expf(m2 - Mn);
    M = Mn;
  }
#pragma unroll
  for (int off = 1; off < 64; off <<= 1) {
    float m2 = __shfl_xor(M, off);
    float l2 = __shfl_xor(L, off);
    float Mn = fmaxf(M, m2);
    L = L * __expf(M - Mn) + l2 * __expf(m2 - Mn);
    M = Mn;
  }
  if (lane == 0) {
    float lse = M + logf(L);
    int t = tgt[row];
    rl[row] = (t != IGNORE_INDEX) ? (lse - tl[row]) : 0.f;
  }
}

// ------------------------------------------------------------- final reduce
__global__ __launch_bounds__(256)
void final_kernel(const float* __restrict__ rl, const int* __restrict__ tgt,
                  float* __restrict__ out) {
  __shared__ float ss[4];
  __shared__ float sc[4];
  float s = 0.f, c = 0.f;
  for (int r = threadIdx.x; r < BT; r += 256) {
    s += rl[r];
    c += (tgt[r] != IGNORE_INDEX) ? 1.f : 0.f;
  }
#pragma unroll
  for (int off = 32; off > 0; off >>= 1) {
    s += __shfl_xor(s, off);
    c += __shfl_xor(c, off);
  }
  int w = threadIdx.x >> 6;
  if ((threadIdx.x & 63) == 0) { ss[w] = s; sc[w] = c; }
  __syncthreads();
  if (threadIdx.x == 0) {
    float S = ss[0] + ss[1] + ss[2] + ss[3];
    float C = sc[0] + sc[1] + sc[2] + sc[3];
    out[0] = S / fmaxf(C, 1.f);
  }
}

extern "C" void kernel_launch(void* const* d_in, const int* in_sizes, int n_in,
                              void* d_out, int out_size, void* d_ws, size_t ws_size,
                              hipStream_t stream) {
  const float* hs  = (const float*)d_in[0];   // hidden_states [BT][H] fp32
  const float* wt  = (const float*)d_in[1];   // weight [V][H] fp32
  const int*   tgt = (const int*)d_in[2];     // targets [BT]
  float*       out = (float*)d_out;

  char* ws = (char*)d_ws;
  size_t off = 0;
  auto alloc = [&](size_t bytes) -> void* {
    void* p = ws + off;
    off += (bytes + 255) & ~(size_t)255;
    return p;
  };
  unsigned char* wf8 = (unsigned char*)alloc((size_t)V * H);        // 65.5 MB packed
  unsigned char* hf8 = (unsigned char*)alloc((size_t)BT * H);       // 8.4 MB packed
  float* pm = (float*)alloc((size_t)NTILES * BT * 4);               // 2.0 MB
  float* pl = (float*)alloc((size_t)NTILES * BT * 4);               // 2.0 MB
  float* tl = (float*)alloc((size_t)BT * 4);
  float* rl = (float*)alloc((size_t)BT * 4);
  (void)ws_size; (void)in_sizes; (void)n_in; (void)out_size;

  // pack tasks: one wave per (16-row group, K-tile)
  cvt_pack_kernel<<<(V / 16) * KT / 4, 256, 0, stream>>>(wt, wf8, (V / 16) * KT);
  cvt_pack_kernel<<<(BT / 16) * KT / 4, 256, 0, stream>>>(hs, hf8, (BT / 16) * KT);

  gemm_lse_kernel<<<NWG, 512, 0, stream>>>(hf8, wf8, tgt, pm, pl, tl);

  row_lse_kernel<<<BT / 4, 256, 0, stream>>>(pm, pl, tl, tgt, rl);
  final_kernel<<<1, 256, 0, stream>>>(rl, tgt, out);
}